// Round 7
// baseline (950.619 us; speedup 1.0000x reference)
//
#include <hip/hip_runtime.h>
#include <hip/hip_fp16.h>
#include <hip/hip_bf16.h>
#include <math.h>

#define BB 2
#define SS 2048
#define HH 16
#define TOPK 512
#define ROWS (BB*SS)
#define KDIM 1024
#define KP 3072      // 3*KDIM (split-bf16 tripled K)
#define NCAT 324     // 256 qi | 64 ki | 4 w

using bf16x8 = __attribute__((ext_vector_type(8))) short;
using f32x4  = __attribute__((ext_vector_type(4))) float;
typedef _Float16 h2f __attribute__((ext_vector_type(2)));
typedef unsigned int u32;

__device__ __forceinline__ float fdot2(u32 a, u32 b, float c) {
#if defined(__has_builtin) && __has_builtin(__builtin_amdgcn_fdot2)
  return __builtin_amdgcn_fdot2(__builtin_bit_cast(h2f, a), __builtin_bit_cast(h2f, b), c, false);
#else
  float d;
  asm volatile("v_dot2_f32_f16 %0, %1, %2, %3" : "=v"(d) : "v"(a), "v"(b), "v"(c));
  return d;
#endif
}

__device__ __forceinline__ void gload16(const void* g, void* l) {
  __builtin_amdgcn_global_load_lds(
      (const __attribute__((address_space(1))) u32*)g,
      (__attribute__((address_space(3))) u32*)l, 16, 0, 0);
}

__device__ __forceinline__ void split_bf16(float f, short& hi, short& lo) {
  __hip_bfloat16 h = __float2bfloat16(f);
  float fh = __bfloat162float(h);
  __hip_bfloat16 l = __float2bfloat16(f - fh);
  hi = *reinterpret_cast<short*>(&h);
  lo = *reinterpret_cast<short*>(&l);
}

__device__ __forceinline__ unsigned fkey(float f) {
  unsigned u = __float_as_uint(f);
  if ((u << 1) == 0u) u = 0u;             // canonicalize -0.0 -> +0.0
  return (u & 0x80000000u) ? ~u : (u | 0x80000000u);
}

__global__ void rope_tab_k(float* __restrict__ ct, float* __restrict__ st) {
  int idx = blockIdx.x * blockDim.x + threadIdx.x;
  if (idx >= SS * 32) return;
  int s = idx >> 5, j = idx & 31;
  float theta = 1.0f / powf(10000.0f, (float)(2 * j) / 64.0f);
  float ang = (float)s * theta;
  float sv, cv;
  sincosf(ang, &sv, &cv);
  ct[idx] = cv;
  st[idx] = sv;
}

// X[M][1024] fp32 -> A[M][3072] bf16 triplets (hi,hi,lo)
__global__ __launch_bounds__(256) void pack_a_k(
    const float* __restrict__ X, short* __restrict__ A, int total4)
{
  int idx = blockIdx.x * 256 + threadIdx.x;
  if (idx >= total4) return;
  float4 v = ((const float4*)X)[idx];
  float a4[4] = {v.x, v.y, v.z, v.w};
  short o[12];
#pragma unroll
  for (int j = 0; j < 4; ++j) {
    short hs, ls; split_bf16(a4[j], hs, ls);
    o[3*j] = hs; o[3*j+1] = hs; o[3*j+2] = ls;
  }
  short* op = A + (size_t)idx * 12;
  *(short4*)(op)     = *(short4*)&o[0];
  *(short4*)(op + 4) = *(short4*)&o[4];
  *(short4*)(op + 8) = *(short4*)&o[8];
}

// W[K=1024][Nw] fp32 -> BT rows [n][3072] bf16 triplets (hi,lo,hi)
__global__ __launch_bounds__(256) void pack_bt_k(
    const float* __restrict__ W, short* __restrict__ BT, int Nw)
{
  __shared__ float tile[32][33];
  int kb = blockIdx.y * 32, nb = blockIdx.x * 32;
  int tx = threadIdx.x & 31, ty = threadIdx.x >> 5;
  for (int yy = ty; yy < 32; yy += 8) {
    float v = 0.f;
    if (nb + tx < Nw) v = W[(size_t)(kb + yy) * Nw + nb + tx];
    tile[yy][tx] = v;
  }
  __syncthreads();
  for (int yy = ty; yy < 32; yy += 8) {
    int n = nb + yy;
    if (n >= Nw) continue;
    int k = kb + tx;
    float f = tile[tx][yy];
    short hs, ls; split_bf16(f, hs, ls);
    short* orow = BT + (size_t)n * KP + 3 * k;
    orow[0] = hs; orow[1] = ls; orow[2] = hs;
  }
}

// Wcat[k][0:256]=Wq, [256:320]=Wk, [320:324]=Ww
__global__ __launch_bounds__(256) void pack_wcat_k(
    const float* __restrict__ Wq, const float* __restrict__ Wk,
    const float* __restrict__ Ww, float* __restrict__ Wcat)
{
  int idx = blockIdx.x * 256 + threadIdx.x;
  if (idx >= 1024 * NCAT) return;
  int k = idx / NCAT, n = idx - k * NCAT;
  float v;
  if (n < 256)      v = Wq[(size_t)k * 256 + n];
  else if (n < 320) v = Wk[(size_t)k * 64 + (n - 256)];
  else              v = Ww[(size_t)k * 4 + (n - 320)];
  Wcat[idx] = v;
}

// bf16 MFMA GEMM: C[M][N] = A[M][Kp]*BT[N][Kp]^T. 128x128, BK=64, 4 waves,
// global_load_lds (width=16) staging.
__global__ __launch_bounds__(256) void gemm_bf16(
    const short* __restrict__ A, const short* __restrict__ BT,
    float* __restrict__ C, int M, int N, int Kp)
{
  __shared__ short As[128 * 64];
  __shared__ short Bs[128 * 64];
  const int tid = threadIdx.x;
  const int lane = tid & 63;
  const int wv = tid >> 6;
  const int m0 = blockIdx.y * 128, n0 = blockIdx.x * 128;
  const int wr = (wv >> 1) * 64, wc = (wv & 1) * 64;
  f32x4 acc[4][4];
#pragma unroll
  for (int i = 0; i < 4; ++i)
#pragma unroll
    for (int j = 0; j < 4; ++j)
#pragma unroll
      for (int r = 0; r < 4; ++r) acc[i][j][r] = 0.0f;

  const int rsel = lane & 15;
  const int lrow = lane >> 3;          // 0..7
  const int lcol = (lane & 7) * 8;     // shorts
  for (int k0 = 0; k0 < Kp; k0 += 64) {
#pragma unroll
    for (int q = 0; q < 4; ++q) {
      int c = wv * 4 + q;              // chunk 0..15 (8 rows each)
      int row = c * 8 + lrow;
      gload16(A  + (size_t)(m0 + row) * Kp + k0 + lcol, &As[c * 512]);
      gload16(BT + (size_t)(n0 + row) * Kp + k0 + lcol, &Bs[c * 512]);
    }
    __syncthreads();
#pragma unroll
    for (int kk = 0; kk < 2; ++kk) {
      bf16x8 af[4], bfr[4];
      int kof = kk * 32 + (lane >> 4) * 8;
#pragma unroll
      for (int i = 0; i < 4; ++i) {
        af[i]  = *(const bf16x8*)&As[(wr + i * 16 + rsel) * 64 + kof];
        bfr[i] = *(const bf16x8*)&Bs[(wc + i * 16 + rsel) * 64 + kof];
      }
#pragma unroll
      for (int i = 0; i < 4; ++i)
#pragma unroll
        for (int j = 0; j < 4; ++j)
          acc[i][j] = __builtin_amdgcn_mfma_f32_16x16x32_bf16(af[i], bfr[j], acc[i][j], 0, 0, 0);
    }
    __syncthreads();
  }
  const int er = m0 + wr + (lane >> 4) * 4;
  const int ec = n0 + wc + rsel;
#pragma unroll
  for (int i = 0; i < 4; ++i)
#pragma unroll
    for (int j = 0; j < 4; ++j)
#pragma unroll
      for (int r = 0; r < 4; ++r)
        C[(size_t)(er + i * 16 + r) * N + ec + j * 16] = acc[i][j][r];
}

// fp32 GEMM for the precision-critical indexer projections, 128x128, BK=16.
template<bool BND>
__global__ __launch_bounds__(256) void gemm128f(
    const float* __restrict__ A, const float* __restrict__ Bw, float* __restrict__ C,
    int M, int N, int K)
{
  __shared__ float As[16][132];
  __shared__ float Bs[16][132];
  int n0 = blockIdx.x * 128, m0 = blockIdx.y * 128;
  int tid = threadIdx.x;
  int tm = (tid >> 4) << 3;
  int tn = (tid & 15) << 3;
  float acc[8][8];
#pragma unroll
  for (int i = 0; i < 8; ++i)
#pragma unroll
    for (int j = 0; j < 8; ++j) acc[i][j] = 0.0f;

  for (int k0 = 0; k0 < K; k0 += 16) {
#pragma unroll
    for (int q = 0; q < 2; ++q) {
      int lin = tid * 4 + q * 1024;
      int row = lin >> 4, kk = lin & 15;
      float4 av = *(const float4*)(A + (size_t)(m0 + row) * K + k0 + kk);
      As[kk + 0][row] = av.x; As[kk + 1][row] = av.y;
      As[kk + 2][row] = av.z; As[kk + 3][row] = av.w;
      int bk = lin >> 7, bc = lin & 127;
      float4 bv;
      if (!BND || (n0 + bc) < N)
        bv = *(const float4*)(Bw + (size_t)(k0 + bk) * N + n0 + bc);
      else
        bv = make_float4(0.f, 0.f, 0.f, 0.f);
      *(float4*)&Bs[bk][bc] = bv;
    }
    __syncthreads();
#pragma unroll
    for (int k = 0; k < 16; ++k) {
      float a[8], bb[8];
      *(float4*)&a[0]  = *(const float4*)&As[k][tm];
      *(float4*)&a[4]  = *(const float4*)&As[k][tm + 4];
      *(float4*)&bb[0] = *(const float4*)&Bs[k][tn];
      *(float4*)&bb[4] = *(const float4*)&Bs[k][tn + 4];
#pragma unroll
      for (int i = 0; i < 8; ++i)
#pragma unroll
        for (int j = 0; j < 8; ++j)
          acc[i][j] = fmaf(a[i], bb[j], acc[i][j]);
    }
    __syncthreads();
  }
#pragma unroll
  for (int i = 0; i < 8; ++i) {
    size_t m = (size_t)(m0 + tm + i);
    float* crow = C + m * (size_t)N;
#pragma unroll
    for (int jc = 0; jc < 2; ++jc) {
      int cb = n0 + tn + jc * 4;
      if (!BND || cb < N) {
        *(float4*)(crow + cb) = make_float4(acc[i][jc*4], acc[i][jc*4+1],
                                            acc[i][jc*4+2], acc[i][jc*4+3]);
      }
    }
  }
}

// C[M][3072] -> RoPE(q,k) + fp16 cast; Qh/Kh/Vh all fp16
__global__ __launch_bounds__(256) void qkv_post_k(
    const float* __restrict__ C, const float* __restrict__ ct, const float* __restrict__ st,
    __half* __restrict__ Qh, __half* __restrict__ Kh, __half* __restrict__ Vh)
{
  int idx = blockIdx.x * 256 + threadIdx.x;
  if (idx >= ROWS * 384) return;
  int m = idx / 384;
  int g = idx - m * 384;
  int col0 = g * 8;
  const float* cp = C + (size_t)m * 3072 + col0;
  float4 v0 = *(const float4*)cp;
  float4 v1 = *(const float4*)(cp + 4);
  float a[8] = {v0.x, v0.y, v0.z, v0.w, v1.x, v1.y, v1.z, v1.w};
  int sec = col0 >> 10;
  int cin = col0 & 1023;
  size_t orow = (size_t)m * 1024 + cin;
  if (sec == 2) {
    __half2 hh[4];
#pragma unroll
    for (int c = 0; c < 4; ++c) hh[c] = __floats2half2_rn(a[2*c], a[2*c+1]);
    *(float4*)(Vh + orow) = *(float4*)hh;
  } else {
    int t = m & (SS - 1);
    int jb = (cin & 63) >> 1;
    float o[8];
#pragma unroll
    for (int c = 0; c < 4; ++c) {
      float cv = ct[t * 32 + jb + c], sv = st[t * 32 + jb + c];
      float x1 = a[2*c], x2 = a[2*c+1];
      o[2*c]   = x1 * cv - x2 * sv;
      o[2*c+1] = x2 * cv + x1 * sv;
    }
    __half2 hh[4];
#pragma unroll
    for (int c = 0; c < 4; ++c) hh[c] = __floats2half2_rn(o[2*c], o[2*c+1]);
    __half* dst = (sec == 0) ? Qh : Kh;
    *(float4*)(dst + orow) = *(float4*)hh;
  }
}

// Per (b,t): indexer scores for s<=t from Ccat (stride NCAT), exact top-512.
__global__ __launch_bounds__(256) void idx_topk_k(
    const float* __restrict__ Ccat, int* __restrict__ sel)
{
  int t = blockIdx.x, b = blockIdx.y;
  int tid = threadIdx.x;
  int* srow = sel + ((size_t)b * SS + t) * TOPK;
  if (t < TOPK) {  // -1e9 ties => selection is exactly [0..511]
    for (int i = tid; i < TOPK; i += 256) srow[i] = i;
    return;
  }
  __shared__ float sc[SS];
  __shared__ unsigned hist[256];
  __shared__ unsigned hs[256];
  __shared__ unsigned s_bsel, s_above, s_cnt;

  const float4* qrow = (const float4*)(Ccat + ((size_t)b * SS + t) * NCAT);
  const float* wrow = Ccat + ((size_t)b * SS + t) * NCAT + 320;
  float w0 = wrow[0], w1 = wrow[1], w2 = wrow[2], w3 = wrow[3];

  for (int s = tid; s <= t; s += 256) {
    const float4* kp = (const float4*)(Ccat + ((size_t)b * SS + s) * NCAT + 256);
    float a0 = 0.f, a1 = 0.f, a2 = 0.f, a3 = 0.f;
#pragma unroll
    for (int d4 = 0; d4 < 16; ++d4) {
      float4 kv = kp[d4];
      float4 q0 = qrow[d4];
      float4 q1 = qrow[16 + d4];
      float4 q2 = qrow[32 + d4];
      float4 q3 = qrow[48 + d4];
      a0 += q0.x * kv.x + q0.y * kv.y + q0.z * kv.z + q0.w * kv.w;
      a1 += q1.x * kv.x + q1.y * kv.y + q1.z * kv.z + q1.w * kv.w;
      a2 += q2.x * kv.x + q2.y * kv.y + q2.z * kv.z + q2.w * kv.w;
      a3 += q3.x * kv.x + q3.y * kv.y + q3.z * kv.z + q3.w * kv.w;
    }
    float v = fmaxf(a0, 0.f) * w0 + fmaxf(a1, 0.f) * w1 +
              fmaxf(a2, 0.f) * w2 + fmaxf(a3, 0.f) * w3;
    sc[s] = v;
  }
  __syncthreads();

  unsigned krem = TOPK;
  unsigned prefix = 0;
#pragma unroll 1
  for (int p = 0; p < 4; ++p) {
    int shift = 24 - 8 * p;
    unsigned maskAbove = (p == 0) ? 0u : (0xFFFFFFFFu << (shift + 8));
    hist[tid] = 0u;
    __syncthreads();
    for (int s = tid; s <= t; s += 256) {
      unsigned key = fkey(sc[s]);
      if ((key & maskAbove) == prefix)
        atomicAdd(&hist[(key >> shift) & 255], 1u);
    }
    __syncthreads();
    hs[tid] = hist[tid];
    __syncthreads();
#pragma unroll 1
    for (int off = 1; off < 256; off <<= 1) {
      unsigned v = (tid + off < 256) ? hs[tid + off] : 0u;
      __syncthreads();
      hs[tid] += v;
      __syncthreads();
    }
    unsigned mine = hs[tid];
    unsigned nxt = (tid < 255) ? hs[tid + 1] : 0u;
    if (mine >= krem && nxt < krem) { s_bsel = (unsigned)tid; s_above = nxt; }
    __syncthreads();
    prefix |= (s_bsel << shift);
    krem -= s_above;
    __syncthreads();
  }

  unsigned Tkey = prefix;
  unsigned kfin = krem;
  if (tid == 0) s_cnt = 0u;
  __syncthreads();
  for (int s = tid; s <= t; s += 256) {
    if (fkey(sc[s]) > Tkey) {
      unsigned pp = atomicAdd(&s_cnt, 1u);
      srow[pp] = s;
    }
  }
  __syncthreads();
  unsigned cgt = s_cnt;
  if (tid < 64) {
    unsigned taken = 0;
    for (int s0 = 0; s0 <= t && taken < kfin; s0 += 64) {
      int s = s0 + tid;
      bool pred = (s <= t) && (fkey(sc[s]) == Tkey);
      unsigned long long mba = __ballot(pred);
      unsigned pre = (unsigned)__popcll(mba & ((1ull << tid) - 1ull));
      if (pred && (taken + pre) < kfin) srow[cgt + taken + pre] = s;
      taken += (unsigned)__popcll(mba);
    }
  }
}

// Gather attention, occupancy-optimized: chunked online softmax.
// LDS ~23.4KB -> 6-7 blocks/CU (vs 37.4KB -> 4). Q/K/V fp16; dot2 math.
// 8 chunks x 64 keys: QK->P1 (fp32 scratch) -> online softmax -> Pf (fp16, <=1).
__global__ __launch_bounds__(256, 6) void attn_k(
    const __half* __restrict__ Qh, const __half* __restrict__ Kh, const __half* __restrict__ Vh,
    const int* __restrict__ sel, float* __restrict__ attnO)
{
  int bid = blockIdx.x;
  int xcd = bid & 7, jg = bid >> 3;
  int b = xcd >> 2;
  int t = (xcd & 3) * 512 + jg;
  int tid = threadIdx.x;
  int lane = tid & 63;
  int wv = tid >> 6;
  __shared__ float P1[64][17];                 // 4.3 KB logit scratch (per chunk)
  __shared__ unsigned short Pf[16][514];       // 16.4 KB fp16 probs, head-major, 257-word stride
  __shared__ int sidx[TOPK];                   // 2 KB
  __shared__ float mTab[8][16];                // per-chunk running max per head

  if (t < TOPK) {
    for (int i = tid; i < TOPK; i += 256) sidx[i] = i;
  } else {
    const int* srow = sel + ((size_t)b * SS + t) * TOPK;
    for (int i = tid; i < TOPK; i += 256) sidx[i] = srow[i];
  }
  const size_t brow = (size_t)b * SS;
  const __half* qrow = Qh + (brow + t) * 1024 + lane * 16;
  u32 qq[8];
  *(float4*)&qq[0] = *(const float4*)(qrow);
  *(float4*)&qq[4] = *(const float4*)(qrow + 8);

  const int h = tid >> 4, i0 = tid & 15;       // softmax/PV mapping (16 lanes per head)
  const int h4 = lane >> 2;                    // QK mapping (lane quad per head)
  float m_run = -3.0e38f, S_run = 0.f;

  __syncthreads();

#pragma unroll 1
  for (int c = 0; c < 8; ++c) {
    // --- QK: wave wv computes 16 keys of this chunk ---
    {
      int kbase = c * 64 + wv * 16;
#pragma unroll 1
      for (int u = 0; u < 16; u += 2) {
        int s0 = sidx[kbase + u], s1 = sidx[kbase + u + 1];
        const float4* p0 = (const float4*)(Kh + (brow + s0) * 1024 + lane * 16);
        const float4* p1 = (const float4*)(Kh + (brow + s1) * 1024 + lane * 16);
        u32 ka[8], kb[8];
        *(float4*)&ka[0] = p0[0]; *(float4*)&ka[4] = p0[1];
        *(float4*)&kb[0] = p1[0]; *(float4*)&kb[4] = p1[1];
        float d0 = 0.f, d1 = 0.f;
#pragma unroll
        for (int w = 0; w < 8; ++w) { d0 = fdot2(qq[w], ka[w], d0); d1 = fdot2(qq[w], kb[w], d1); }
        d0 += __shfl_xor(d0, 1); d0 += __shfl_xor(d0, 2);
        d1 += __shfl_xor(d1, 1); d1 += __shfl_xor(d1, 2);
        if ((lane & 3) == 0) {
          P1[wv * 16 + u][h4]     = d0 * 0.125f;
          P1[wv * 16 + u + 1][h4] = d1 * 0.125f;
        }
      }
    }
    __syncthreads();
    // --- online softmax: thread (h,i0) handles keys i0, i0+16, i0+32, i0+48 ---
    {
      float l0 = P1[i0][h], l1 = P1[i0 + 16][h], l2 = P1[i0 + 32][h], l3 = P1[i0 + 48][h];
      float cm = fmaxf(fmaxf(l0, l1), fmaxf(l2, l3));
#pragma unroll
      for (int off = 1; off < 16; off <<= 1) cm = fmaxf(cm, __shfl_xor(cm, off));
      float m_new = fmaxf(m_run, cm);
      float fac = __expf(m_run - m_new);       // first chunk: exp(-inf)=0
      float e0 = __expf(l0 - m_new), e1 = __expf(l1 - m_new);
      float e2 = __expf(l2 - m_new), e3 = __expf(l3 - m_new);
      S_run = S_run * fac + (e0 + e1 + e2 + e3);
      m_run = m_new;
      int kb2 = c * 64;
      Pf[h][kb2 + i0]      = __half_as_ushort(__float2half_rn(e0));
      Pf[h][kb2 + i0 + 16] = __half_as_ushort(__float2half_rn(e1));
      Pf[h][kb2 + i0 + 32] = __half_as_ushort(__float2half_rn(e2));
      Pf[h][kb2 + i0 + 48] = __half_as_ushort(__float2half_rn(e3));
      if (i0 == 0) mTab[c][h] = m_new;
    }
    __syncthreads();
  }

  // finalize denom (uniform across the 16-lane group after reduce)
#pragma unroll
  for (int off = 1; off < 16; off <<= 1) S_run += __shfl_xor(S_run, off);

  // --- PV: thread (h, dq) accumulates 4 dims; per-chunk partials scaled by e^(m_c - m_fin) ---
  int dq = (tid & 15) << 2;
  size_t hoff = (size_t)h * 64 + dq;
  const __half* vb = Vh + brow * 1024 + hoff;
  float a0 = 0.f, a1 = 0.f, a2 = 0.f, a3 = 0.f;
  const u32* PfW = (const u32*)(&Pf[h][0]);
#pragma unroll 1
  for (int c = 0; c < 8; ++c) {
    float c0 = 0.f, c1 = 0.f, c2 = 0.f, c3 = 0.f;
#pragma unroll 4
    for (int k2 = 0; k2 < 32; ++k2) {
      int jj = c * 32 + k2;
      u32 pv = PfW[jj];
      int2 ss = *(const int2*)&sidx[2 * jj];
      float2 va = *(const float2*)(vb + (size_t)ss.x * 1024);
      float2 vw = *(const float2*)(vb + (size_t)ss.y * 1024);
      u32 A01 = __float_as_uint(va.x), A23 = __float_as_uint(va.y);
      u32 B01 = __float_as_uint(vw.x), B23 = __float_as_uint(vw.y);
      c0 = fdot2(pv, __builtin_amdgcn_perm(A01, B01, 0x01000504u), c0);
      c1 = fdot2(pv, __builtin_amdgcn_perm(A01, B01, 0x03020706u), c1);
      c2 = fdot2(pv, __builtin_amdgcn_perm(A23, B23, 0x01000504u), c2);
      c3 = fdot2(pv, __builtin_amdgcn_perm(A23, B23, 0x03020706u), c3);
    }
    float scl = __expf(mTab[c][h] - m_run);
    a0 = fmaf(scl, c0, a0); a1 = fmaf(scl, c1, a1);
    a2 = fmaf(scl, c2, a2); a3 = fmaf(scl, c3, a3);
  }
  float inv = 1.0f / S_run;
  *(float4*)(attnO + (brow + t) * 1024 + hoff) =
      make_float4(a0 * inv, a1 * inv, a2 * inv, a3 * inv);
}

extern "C" void kernel_launch(void* const* d_in, const int* in_sizes, int n_in,
                              void* d_out, int out_size, void* d_ws, size_t ws_size,
                              hipStream_t stream) {
  const float* x    = (const float*)d_in[0];
  const float* Wqkv = (const float*)d_in[1];
  const float* Wo   = (const float*)d_in[2];
  const float* Wq   = (const float*)d_in[3];
  const float* Wk   = (const float*)d_in[4];
  const float* Ww   = (const float*)d_in[5];
  float* out = (float*)d_out;

  float* fws = (float*)d_ws;
  size_t o = 0;
  __half* Qh    = (__half*)(fws + o);  o += (size_t)ROWS * 512;
  __half* Kh    = (__half*)(fws + o);  o += (size_t)ROWS * 512;
  __half* Vh    = (__half*)(fws + o);  o += (size_t)ROWS * 512;
  int*    sel   = (int*)(fws + o);     o += (size_t)ROWS * TOPK;
  float*  ct    = fws + o;             o += (size_t)SS * 32;
  float*  st    = fws + o;             o += (size_t)SS * 32;
  float*  Ccat  = fws + o;             o += (size_t)ROWS * NCAT;       // fused qi|ki|w
  short*  BTwo  = (short*)(fws + o);   o += (size_t)1024 * KP / 2;
  short*  BTq   = (short*)(fws + o);   o += (size_t)3072 * KP / 2;
  short*  Ax    = (short*)(fws + o);                                   // aliased region (ROWS*KP shorts):
  float*  attnO = fws + o;                                             //  attnO reuses Ax after qkv gemm
  float*  Wcat  = fws + o + (size_t)ROWS * 1024;                       //  Wcat in tail (after attnO's span; Ax dead by then)
  /* region size */                    o += (size_t)ROWS * KP / 2;
  float*  Cbuf  = fws + o;                                             // aliased region:
  short*  Aattn = (short*)(fws + o);   o += (size_t)ROWS * 3072;       //  Aattn reuses Cbuf

  rope_tab_k<<<dim3((SS * 32 + 255) / 256), dim3(256), 0, stream>>>(ct, st);

  // packs for the two MFMA GEMMs
  pack_a_k<<<dim3(ROWS * KDIM / 4 / 256), dim3(256), 0, stream>>>(x, Ax, ROWS * KDIM / 4);
  pack_bt_k<<<dim3(3072 / 32, 32), dim3(256), 0, stream>>>(Wqkv, BTq, 3072);
  pack_bt_k<<<dim3(1024 / 32, 32), dim3(256), 0, stream>>>(Wo, BTwo, 1024);

  // qkv GEMM (split-bf16 MFMA): Cbuf[4096][3072] = x * Wqkv   (last use of Ax)
  gemm_bf16<<<dim3(3072 / 128, ROWS / 128), dim3(256), 0, stream>>>(
      Ax, BTq, Cbuf, ROWS, 3072, KP);
  qkv_post_k<<<dim3((ROWS * 384 + 255) / 256), dim3(256), 0, stream>>>(Cbuf, ct, st, Qh, Kh, Vh);

  // fused indexer projections in fp32 (bit-identical math to the split version)
  pack_wcat_k<<<dim3((1024 * NCAT + 255) / 256), dim3(256), 0, stream>>>(Wq, Wk, Ww, Wcat);
  gemm128f<true><<<dim3(3, ROWS / 128), dim3(256), 0, stream>>>(x, Wcat, Ccat, ROWS, NCAT, 1024);

  idx_topk_k<<<dim3(SS, BB), dim3(256), 0, stream>>>(Ccat, sel);
  attn_k<<<dim3(ROWS), dim3(256), 0, stream>>>(Qh, Kh, Vh, sel, attnO);

  // out = attn @ Wo (split-bf16 MFMA)
  pack_a_k<<<dim3(ROWS * KDIM / 4 / 256), dim3(256), 0, stream>>>(attnO, Aattn, ROWS * KDIM / 4);
  gemm_bf16<<<dim3(1024 / 128, ROWS / 128), dim3(256), 0, stream>>>(
      Aattn, BTwo, out, ROWS, 1024, KP);
}

// Round 8
// 669.672 us; speedup vs baseline: 1.4195x; 1.4195x over previous
//
#include <hip/hip_runtime.h>
#include <hip/hip_fp16.h>
#include <hip/hip_bf16.h>
#include <math.h>

#define BB 2
#define SS 2048
#define HH 16
#define TOPK 512
#define ROWS (BB*SS)
#define KDIM 1024
#define KP 3072      // 3*KDIM (split-bf16 tripled K)
#define NCAT 324     // 256 qi | 64 ki | 4 w

using bf16x8 = __attribute__((ext_vector_type(8))) short;
using f32x4  = __attribute__((ext_vector_type(4))) float;
typedef _Float16 f16x8 __attribute__((ext_vector_type(8)));
typedef unsigned int u32;

__device__ __forceinline__ void gload16(const void* g, void* l) {
  __builtin_amdgcn_global_load_lds(
      (const __attribute__((address_space(1))) u32*)g,
      (__attribute__((address_space(3))) u32*)l, 16, 0, 0);
}

__device__ __forceinline__ void split_bf16(float f, short& hi, short& lo) {
  __hip_bfloat16 h = __float2bfloat16(f);
  float fh = __bfloat162float(h);
  __hip_bfloat16 l = __float2bfloat16(f - fh);
  hi = *reinterpret_cast<short*>(&h);
  lo = *reinterpret_cast<short*>(&l);
}

__device__ __forceinline__ unsigned fkey(float f) {
  unsigned u = __float_as_uint(f);
  if ((u << 1) == 0u) u = 0u;             // canonicalize -0.0 -> +0.0
  return (u & 0x80000000u) ? ~u : (u | 0x80000000u);
}

__global__ void rope_tab_k(float* __restrict__ ct, float* __restrict__ st) {
  int idx = blockIdx.x * blockDim.x + threadIdx.x;
  if (idx >= SS * 32) return;
  int s = idx >> 5, j = idx & 31;
  float theta = 1.0f / powf(10000.0f, (float)(2 * j) / 64.0f);
  float ang = (float)s * theta;
  float sv, cv;
  sincosf(ang, &sv, &cv);
  ct[idx] = cv;
  st[idx] = sv;
}

// X[M][1024] fp32 -> A[M][3072] bf16 triplets (hi,hi,lo)
__global__ __launch_bounds__(256) void pack_a_k(
    const float* __restrict__ X, short* __restrict__ A, int total4)
{
  int idx = blockIdx.x * 256 + threadIdx.x;
  if (idx >= total4) return;
  float4 v = ((const float4*)X)[idx];
  float a4[4] = {v.x, v.y, v.z, v.w};
  short o[12];
#pragma unroll
  for (int j = 0; j < 4; ++j) {
    short hs, ls; split_bf16(a4[j], hs, ls);
    o[3*j] = hs; o[3*j+1] = hs; o[3*j+2] = ls;
  }
  short* op = A + (size_t)idx * 12;
  *(short4*)(op)     = *(short4*)&o[0];
  *(short4*)(op + 4) = *(short4*)&o[4];
  *(short4*)(op + 8) = *(short4*)&o[8];
}

// W[K=1024][Nw] fp32 -> BT rows [n][3072] bf16 triplets (hi,lo,hi)
__global__ __launch_bounds__(256) void pack_bt_k(
    const float* __restrict__ W, short* __restrict__ BT, int Nw)
{
  __shared__ float tile[32][33];
  int kb = blockIdx.y * 32, nb = blockIdx.x * 32;
  int tx = threadIdx.x & 31, ty = threadIdx.x >> 5;
  for (int yy = ty; yy < 32; yy += 8) {
    float v = 0.f;
    if (nb + tx < Nw) v = W[(size_t)(kb + yy) * Nw + nb + tx];
    tile[yy][tx] = v;
  }
  __syncthreads();
  for (int yy = ty; yy < 32; yy += 8) {
    int n = nb + yy;
    if (n >= Nw) continue;
    int k = kb + tx;
    float f = tile[tx][yy];
    short hs, ls; split_bf16(f, hs, ls);
    short* orow = BT + (size_t)n * KP + 3 * k;
    orow[0] = hs; orow[1] = ls; orow[2] = hs;
  }
}

// Wcat[k][0:256]=Wq, [256:320]=Wk, [320:324]=Ww
__global__ __launch_bounds__(256) void pack_wcat_k(
    const float* __restrict__ Wq, const float* __restrict__ Wk,
    const float* __restrict__ Ww, float* __restrict__ Wcat)
{
  int idx = blockIdx.x * 256 + threadIdx.x;
  if (idx >= 1024 * NCAT) return;
  int k = idx / NCAT, n = idx - k * NCAT;
  float v;
  if (n < 256)      v = Wq[(size_t)k * 256 + n];
  else if (n < 320) v = Wk[(size_t)k * 64 + (n - 256)];
  else              v = Ww[(size_t)k * 4 + (n - 320)];
  Wcat[idx] = v;
}

// bf16 MFMA GEMM: C[M][N] = A[M][Kp]*BT[N][Kp]^T. 128x128, BK=64, 4 waves.
__global__ __launch_bounds__(256) void gemm_bf16(
    const short* __restrict__ A, const short* __restrict__ BT,
    float* __restrict__ C, int M, int N, int Kp)
{
  __shared__ short As[128 * 64];
  __shared__ short Bs[128 * 64];
  const int tid = threadIdx.x;
  const int lane = tid & 63;
  const int wv = tid >> 6;
  const int m0 = blockIdx.y * 128, n0 = blockIdx.x * 128;
  const int wr = (wv >> 1) * 64, wc = (wv & 1) * 64;
  f32x4 acc[4][4];
#pragma unroll
  for (int i = 0; i < 4; ++i)
#pragma unroll
    for (int j = 0; j < 4; ++j)
#pragma unroll
      for (int r = 0; r < 4; ++r) acc[i][j][r] = 0.0f;

  const int rsel = lane & 15;
  const int lrow = lane >> 3;          // 0..7
  const int lcol = (lane & 7) * 8;     // shorts
  for (int k0 = 0; k0 < Kp; k0 += 64) {
#pragma unroll
    for (int q = 0; q < 4; ++q) {
      int c = wv * 4 + q;              // chunk 0..15 (8 rows each)
      int row = c * 8 + lrow;
      gload16(A  + (size_t)(m0 + row) * Kp + k0 + lcol, &As[c * 512]);
      gload16(BT + (size_t)(n0 + row) * Kp + k0 + lcol, &Bs[c * 512]);
    }
    __syncthreads();
#pragma unroll
    for (int kk = 0; kk < 2; ++kk) {
      bf16x8 af[4], bfr[4];
      int kof = kk * 32 + (lane >> 4) * 8;
#pragma unroll
      for (int i = 0; i < 4; ++i) {
        af[i]  = *(const bf16x8*)&As[(wr + i * 16 + rsel) * 64 + kof];
        bfr[i] = *(const bf16x8*)&Bs[(wc + i * 16 + rsel) * 64 + kof];
      }
#pragma unroll
      for (int i = 0; i < 4; ++i)
#pragma unroll
        for (int j = 0; j < 4; ++j)
          acc[i][j] = __builtin_amdgcn_mfma_f32_16x16x32_bf16(af[i], bfr[j], acc[i][j], 0, 0, 0);
    }
    __syncthreads();
  }
  const int er = m0 + wr + (lane >> 4) * 4;
  const int ec = n0 + wc + rsel;
#pragma unroll
  for (int i = 0; i < 4; ++i)
#pragma unroll
    for (int j = 0; j < 4; ++j)
#pragma unroll
      for (int r = 0; r < 4; ++r)
        C[(size_t)(er + i * 16 + r) * N + ec + j * 16] = acc[i][j][r];
}

// fp32 GEMM for the precision-critical indexer projections, 128x128, BK=16.
template<bool BND>
__global__ __launch_bounds__(256) void gemm128f(
    const float* __restrict__ A, const float* __restrict__ Bw, float* __restrict__ C,
    int M, int N, int K)
{
  __shared__ float As[16][132];
  __shared__ float Bs[16][132];
  int n0 = blockIdx.x * 128, m0 = blockIdx.y * 128;
  int tid = threadIdx.x;
  int tm = (tid >> 4) << 3;
  int tn = (tid & 15) << 3;
  float acc[8][8];
#pragma unroll
  for (int i = 0; i < 8; ++i)
#pragma unroll
    for (int j = 0; j < 8; ++j) acc[i][j] = 0.0f;

  for (int k0 = 0; k0 < K; k0 += 16) {
#pragma unroll
    for (int q = 0; q < 2; ++q) {
      int lin = tid * 4 + q * 1024;
      int row = lin >> 4, kk = lin & 15;
      float4 av = *(const float4*)(A + (size_t)(m0 + row) * K + k0 + kk);
      As[kk + 0][row] = av.x; As[kk + 1][row] = av.y;
      As[kk + 2][row] = av.z; As[kk + 3][row] = av.w;
      int bk = lin >> 7, bc = lin & 127;
      float4 bv;
      if (!BND || (n0 + bc) < N)
        bv = *(const float4*)(Bw + (size_t)(k0 + bk) * N + n0 + bc);
      else
        bv = make_float4(0.f, 0.f, 0.f, 0.f);
      *(float4*)&Bs[bk][bc] = bv;
    }
    __syncthreads();
#pragma unroll
    for (int k = 0; k < 16; ++k) {
      float a[8], bb[8];
      *(float4*)&a[0]  = *(const float4*)&As[k][tm];
      *(float4*)&a[4]  = *(const float4*)&As[k][tm + 4];
      *(float4*)&bb[0] = *(const float4*)&Bs[k][tn];
      *(float4*)&bb[4] = *(const float4*)&Bs[k][tn + 4];
#pragma unroll
      for (int i = 0; i < 8; ++i)
#pragma unroll
        for (int j = 0; j < 8; ++j)
          acc[i][j] = fmaf(a[i], bb[j], acc[i][j]);
    }
    __syncthreads();
  }
#pragma unroll
  for (int i = 0; i < 8; ++i) {
    size_t m = (size_t)(m0 + tm + i);
    float* crow = C + m * (size_t)N;
#pragma unroll
    for (int jc = 0; jc < 2; ++jc) {
      int cb = n0 + tn + jc * 4;
      if (!BND || cb < N) {
        *(float4*)(crow + cb) = make_float4(acc[i][jc*4], acc[i][jc*4+1],
                                            acc[i][jc*4+2], acc[i][jc*4+3]);
      }
    }
  }
}

// C[M][3072] -> RoPE(q,k) + fp16 cast; Q pre-scaled by 1/8 (logit scale).
__global__ __launch_bounds__(256) void qkv_post_k(
    const float* __restrict__ C, const float* __restrict__ ct, const float* __restrict__ st,
    __half* __restrict__ Qh, __half* __restrict__ Kh, __half* __restrict__ Vh)
{
  int idx = blockIdx.x * 256 + threadIdx.x;
  if (idx >= ROWS * 384) return;
  int m = idx / 384;
  int g = idx - m * 384;
  int col0 = g * 8;
  const float* cp = C + (size_t)m * 3072 + col0;
  float4 v0 = *(const float4*)cp;
  float4 v1 = *(const float4*)(cp + 4);
  float a[8] = {v0.x, v0.y, v0.z, v0.w, v1.x, v1.y, v1.z, v1.w};
  int sec = col0 >> 10;
  int cin = col0 & 1023;
  size_t orow = (size_t)m * 1024 + cin;
  if (sec == 2) {
    __half2 hh[4];
#pragma unroll
    for (int c = 0; c < 4; ++c) hh[c] = __floats2half2_rn(a[2*c], a[2*c+1]);
    *(float4*)(Vh + orow) = *(float4*)hh;
  } else {
    int t = m & (SS - 1);
    int jb = (cin & 63) >> 1;
    float o[8];
#pragma unroll
    for (int c = 0; c < 4; ++c) {
      float cv = ct[t * 32 + jb + c], sv = st[t * 32 + jb + c];
      float x1 = a[2*c], x2 = a[2*c+1];
      o[2*c]   = x1 * cv - x2 * sv;
      o[2*c+1] = x2 * cv + x1 * sv;
    }
    if (sec == 0) {
#pragma unroll
      for (int c = 0; c < 8; ++c) o[c] *= 0.125f;   // fold 1/sqrt(64)
    }
    __half2 hh[4];
#pragma unroll
    for (int c = 0; c < 4; ++c) hh[c] = __floats2half2_rn(o[2*c], o[2*c+1]);
    __half* dst = (sec == 0) ? Qh : Kh;
    *(float4*)(dst + orow) = *(float4*)hh;
  }
}

// Vh (b,s,h*64+d) -> VhT [(b*16+h)*64+d][s]
__global__ __launch_bounds__(256) void vt_k(
    const __half* __restrict__ Vh, __half* __restrict__ VhT)
{
  int st = blockIdx.x, bh = blockIdx.y;
  int b = bh >> 4, h = bh & 15;
  int s0 = st * 64;
  __shared__ __half tile[64][65];
  int tid = threadIdx.x;
#pragma unroll
  for (int rnd = 0; rnd < 2; ++rnd) {
    int row = (tid >> 3) + rnd * 32;
    int c8 = (tid & 7) * 8;
    *(float4*)&tile[row][c8] =
        *(const float4*)(Vh + ((size_t)b * SS + s0 + row) * 1024 + h * 64 + c8);
  }
  __syncthreads();
#pragma unroll
  for (int rnd = 0; rnd < 2; ++rnd) {
    int d = (tid >> 3) + rnd * 32;
    int s8 = (tid & 7) * 8;
    __half tmp[8];
#pragma unroll
    for (int j = 0; j < 8; ++j) tmp[j] = tile[s8 + j][d];
    *(float4*)(VhT + ((size_t)bh * 64 + d) * 2048 + s0 + s8) = *(float4*)tmp;
  }
}

// sel -> per-(b,t) 2048-bit selection mask (64 u32 words)
__global__ __launch_bounds__(256) void mask_k(
    const int* __restrict__ sel, u32* __restrict__ msk)
{
  int row = blockIdx.x;            // 0..ROWS-1
  int t = row & (SS - 1);
  int tid = threadIdx.x;
  __shared__ u32 w[64];
  if (tid < 64) w[tid] = (t < TOPK) ? ((tid < 16) ? 0xFFFFFFFFu : 0u) : 0u;
  __syncthreads();
  if (t >= TOPK) {
    for (int i = tid; i < TOPK; i += 256) {
      int s = sel[(size_t)row * TOPK + i];
      atomicOr(&w[s >> 5], 1u << (s & 31));
    }
  }
  __syncthreads();
  if (tid < 64) msk[(size_t)row * 64 + tid] = w[tid];
}

// Per (b,t): indexer scores for s<=t from Ccat (stride NCAT), exact top-512.
__global__ __launch_bounds__(256) void idx_topk_k(
    const float* __restrict__ Ccat, int* __restrict__ sel)
{
  int t = blockIdx.x, b = blockIdx.y;
  int tid = threadIdx.x;
  int* srow = sel + ((size_t)b * SS + t) * TOPK;
  if (t < TOPK) {  // -1e9 ties => selection is exactly [0..511]
    for (int i = tid; i < TOPK; i += 256) srow[i] = i;
    return;
  }
  __shared__ float sc[SS];
  __shared__ unsigned hist[256];
  __shared__ unsigned hs[256];
  __shared__ unsigned s_bsel, s_above, s_cnt;

  const float4* qrow = (const float4*)(Ccat + ((size_t)b * SS + t) * NCAT);
  const float* wrow = Ccat + ((size_t)b * SS + t) * NCAT + 320;
  float w0 = wrow[0], w1 = wrow[1], w2 = wrow[2], w3 = wrow[3];

  for (int s = tid; s <= t; s += 256) {
    const float4* kp = (const float4*)(Ccat + ((size_t)b * SS + s) * NCAT + 256);
    float a0 = 0.f, a1 = 0.f, a2 = 0.f, a3 = 0.f;
#pragma unroll
    for (int d4 = 0; d4 < 16; ++d4) {
      float4 kv = kp[d4];
      float4 q0 = qrow[d4];
      float4 q1 = qrow[16 + d4];
      float4 q2 = qrow[32 + d4];
      float4 q3 = qrow[48 + d4];
      a0 += q0.x * kv.x + q0.y * kv.y + q0.z * kv.z + q0.w * kv.w;
      a1 += q1.x * kv.x + q1.y * kv.y + q1.z * kv.z + q1.w * kv.w;
      a2 += q2.x * kv.x + q2.y * kv.y + q2.z * kv.z + q2.w * kv.w;
      a3 += q3.x * kv.x + q3.y * kv.y + q3.z * kv.z + q3.w * kv.w;
    }
    float v = fmaxf(a0, 0.f) * w0 + fmaxf(a1, 0.f) * w1 +
              fmaxf(a2, 0.f) * w2 + fmaxf(a3, 0.f) * w3;
    sc[s] = v;
  }
  __syncthreads();

  unsigned krem = TOPK;
  unsigned prefix = 0;
#pragma unroll 1
  for (int p = 0; p < 4; ++p) {
    int shift = 24 - 8 * p;
    unsigned maskAbove = (p == 0) ? 0u : (0xFFFFFFFFu << (shift + 8));
    hist[tid] = 0u;
    __syncthreads();
    for (int s = tid; s <= t; s += 256) {
      unsigned key = fkey(sc[s]);
      if ((key & maskAbove) == prefix)
        atomicAdd(&hist[(key >> shift) & 255], 1u);
    }
    __syncthreads();
    hs[tid] = hist[tid];
    __syncthreads();
#pragma unroll 1
    for (int off = 1; off < 256; off <<= 1) {
      unsigned v = (tid + off < 256) ? hs[tid + off] : 0u;
      __syncthreads();
      hs[tid] += v;
      __syncthreads();
    }
    unsigned mine = hs[tid];
    unsigned nxt = (tid < 255) ? hs[tid + 1] : 0u;
    if (mine >= krem && nxt < krem) { s_bsel = (unsigned)tid; s_above = nxt; }
    __syncthreads();
    prefix |= (s_bsel << shift);
    krem -= s_above;
    __syncthreads();
  }

  unsigned Tkey = prefix;
  unsigned kfin = krem;
  if (tid == 0) s_cnt = 0u;
  __syncthreads();
  for (int s = tid; s <= t; s += 256) {
    if (fkey(sc[s]) > Tkey) {
      unsigned pp = atomicAdd(&s_cnt, 1u);
      srow[pp] = s;
    }
  }
  __syncthreads();
  unsigned cgt = s_cnt;
  if (tid < 64) {
    unsigned taken = 0;
    for (int s0 = 0; s0 <= t && taken < kfin; s0 += 64) {
      int s = s0 + tid;
      bool pred = (s <= t) && (fkey(sc[s]) == Tkey);
      unsigned long long mba = __ballot(pred);
      unsigned pre = (unsigned)__popcll(mba & ((1ull << tid) - 1ull));
      if (pred && (taken + pre) < kfin) srow[cgt + taken + pre] = s;
      taken += (unsigned)__popcll(mba);
    }
  }
}

// Dense masked flash attention, f16 MFMA. Block = (b,h, 64-query tile).
// Iterates all 2048 keys in 64-key tiles with the 512-selected mask -> exact.
__global__ __launch_bounds__(256) void attn_dense_k(
    const __half* __restrict__ Qh, const __half* __restrict__ Kh,
    const __half* __restrict__ VhT, const u32* __restrict__ msk,
    float* __restrict__ attnO)
{
  int bid = blockIdx.x;
  int xcd = bid & 7, loc = bid >> 3;
  int bh = xcd * 4 + (loc >> 5);       // 4 (b,h) pairs per XCD -> K/V L2-resident
  int qt = loc & 31;
  int b = bh >> 4, h = bh & 15;
  int t0 = qt * 64;

  const int tid = threadIdx.x;
  const int lane = tid & 63;
  const int wv = tid >> 6;
  const int l15 = lane & 15;
  const int g = lane >> 4;

  __shared__ short lds[12800];          // Ks 4096 | Vt 4096 | Ps 4*1088 | mask 256
  short* Ks = lds;                      // [64 keys][8 chunks] XOR-swizzled
  short* Vt = lds + 4096;               // [64 dims][8 chunks] XOR-swizzled
  short* Ps = lds + 8192 + wv * 1088;   // per-wave [16 queries][68]
  u32* mlds = (u32*)(lds + 12544);      // [64 queries][2 words]

  const size_t brow = (size_t)b * SS;

  // Q A-fragments (m = this wave's 16 queries), resident in regs
  f16x8 qf0, qf1;
  {
    const __half* qp = Qh + (brow + t0 + wv * 16 + l15) * 1024 + h * 64 + g * 8;
    qf0 = *(const f16x8*)(qp);
    qf1 = *(const f16x8*)(qp + 32);
  }

  f32x4 accO[4];
#pragma unroll
  for (int n2 = 0; n2 < 4; ++n2)
#pragma unroll
    for (int r = 0; r < 4; ++r) accO[n2][r] = 0.f;
  float mRun[4] = {-1e30f, -1e30f, -1e30f, -1e30f};
  float sRun[4] = {0.f, 0.f, 0.f, 0.f};

  const int srow = lane >> 3;           // staging row within 8-row group
  const int scp  = (lane & 7) ^ srow;   // pre-swizzled source chunk

#pragma unroll 1
  for (int kt = 0; kt < 32; ++kt) {
    int kt0 = kt * 64;
    // ---- stage K tile, V^T tile (DMA, linear dest + inverse-swizzled src), mask ----
#pragma unroll
    for (int q = 0; q < 2; ++q) {
      int j = wv * 2 + q;
      gload16(Kh + (brow + kt0 + j * 8 + srow) * 1024 + h * 64 + scp * 8, Ks + j * 512);
      gload16(VhT + ((size_t)(bh * 64 + j * 8 + srow)) * 2048 + kt0 + scp * 8, Vt + j * 512);
    }
    if (tid < 128)
      mlds[tid] = msk[(brow + t0 + (tid >> 1)) * 64 + kt * 2 + (tid & 1)];
    __syncthreads();

    // ---- QK^T: D[m=query][n=key] ----
    f32x4 s4[4];
#pragma unroll
    for (int ns = 0; ns < 4; ++ns) {
#pragma unroll
      for (int r = 0; r < 4; ++r) s4[ns][r] = 0.f;
      int rowk = ns * 16 + l15;
      int cp0 = g ^ (rowk & 7);
      int cp1 = (4 + g) ^ (rowk & 7);
      f16x8 kf0 = *(const f16x8*)&Ks[rowk * 64 + cp0 * 8];
      f16x8 kf1 = *(const f16x8*)&Ks[rowk * 64 + cp1 * 8];
      s4[ns] = __builtin_amdgcn_mfma_f32_16x16x32_f16(qf0, kf0, s4[ns], 0, 0, 0);
      s4[ns] = __builtin_amdgcn_mfma_f32_16x16x32_f16(qf1, kf1, s4[ns], 0, 0, 0);
    }

    // ---- masked online softmax (per query row r; keys across l15 x ns) ----
#pragma unroll
    for (int r = 0; r < 4; ++r) {
      int qb2 = (wv * 16 + g * 4 + r) * 2;
      u32 w0 = mlds[qb2];
      u32 w1 = mlds[qb2 + 1];
      float le[4];
#pragma unroll
      for (int ns = 0; ns < 4; ++ns) {
        u32 w = (ns < 2) ? w0 : w1;
        int bit = (ns & 1) * 16 + l15;
        float l = s4[ns][r];
        le[ns] = ((w >> bit) & 1u) ? l : -1e30f;
      }
      float cm = fmaxf(fmaxf(le[0], le[1]), fmaxf(le[2], le[3]));
      cm = fmaxf(cm, __shfl_xor(cm, 1));
      cm = fmaxf(cm, __shfl_xor(cm, 2));
      cm = fmaxf(cm, __shfl_xor(cm, 4));
      cm = fmaxf(cm, __shfl_xor(cm, 8));
      float mn = fmaxf(mRun[r], cm);
      float fac = __expf(mRun[r] - mn);
      mRun[r] = mn;
      float sum = 0.f;
#pragma unroll
      for (int ns = 0; ns < 4; ++ns) {
        float ee = __expf(le[ns] - mn);
        ee = (le[ns] < -1e29f) ? 0.f : ee;   // masked -> exactly 0
        sum += ee;
        Ps[(g * 4 + r) * 68 + ns * 16 + l15] =
            (short)__half_as_ushort(__float2half_rn(ee));
      }
      sum += __shfl_xor(sum, 1);
      sum += __shfl_xor(sum, 2);
      sum += __shfl_xor(sum, 4);
      sum += __shfl_xor(sum, 8);
      sRun[r] = sRun[r] * fac + sum;
#pragma unroll
      for (int n2 = 0; n2 < 4; ++n2) accO[n2][r] *= fac;
    }

    // ---- PV: D[m=query][n=dim] += P * V ----
    f16x8 pa0, pa1;
    {
      const short* pp = &Ps[l15 * 68 + g * 8];
      float2 lo0 = *(const float2*)(pp);
      float2 hi0 = *(const float2*)(pp + 4);
      float2 lo1 = *(const float2*)(pp + 32);
      float2 hi1 = *(const float2*)(pp + 36);
      float4 c0 = make_float4(lo0.x, lo0.y, hi0.x, hi0.y);
      float4 c1 = make_float4(lo1.x, lo1.y, hi1.x, hi1.y);
      pa0 = *(const f16x8*)&c0;
      pa1 = *(const f16x8*)&c1;
    }
#pragma unroll
    for (int n2 = 0; n2 < 4; ++n2) {
      int rowd = n2 * 16 + l15;
      int cp0 = g ^ (rowd & 7);
      int cp1 = (4 + g) ^ (rowd & 7);
      f16x8 vf0 = *(const f16x8*)&Vt[rowd * 64 + cp0 * 8];
      f16x8 vf1 = *(const f16x8*)&Vt[rowd * 64 + cp1 * 8];
      accO[n2] = __builtin_amdgcn_mfma_f32_16x16x32_f16(pa0, vf0, accO[n2], 0, 0, 0);
      accO[n2] = __builtin_amdgcn_mfma_f32_16x16x32_f16(pa1, vf1, accO[n2], 0, 0, 0);
    }
    __syncthreads();
  }

#pragma unroll
  for (int r = 0; r < 4; ++r) {
    float inv = 1.0f / sRun[r];
    size_t orow = (brow + t0 + wv * 16 + g * 4 + r) * (size_t)1024 + h * 64;
#pragma unroll
    for (int n2 = 0; n2 < 4; ++n2)
      attnO[orow + n2 * 16 + l15] = accO[n2][r] * inv;
  }
}

extern "C" void kernel_launch(void* const* d_in, const int* in_sizes, int n_in,
                              void* d_out, int out_size, void* d_ws, size_t ws_size,
                              hipStream_t stream) {
  const float* x    = (const float*)d_in[0];
  const float* Wqkv = (const float*)d_in[1];
  const float* Wo   = (const float*)d_in[2];
  const float* Wq   = (const float*)d_in[3];
  const float* Wk   = (const float*)d_in[4];
  const float* Ww   = (const float*)d_in[5];
  float* out = (float*)d_out;

  float* fws = (float*)d_ws;
  size_t o = 0;
  __half* Qh    = (__half*)(fws + o);  o += (size_t)ROWS * 512;
  __half* Kh    = (__half*)(fws + o);  o += (size_t)ROWS * 512;
  __half* Vh    = (__half*)(fws + o);  o += (size_t)ROWS * 512;
  int*    sel   = (int*)(fws + o);     o += (size_t)ROWS * TOPK;
  float*  ct    = fws + o;             o += (size_t)SS * 32;
  float*  st    = fws + o;             o += (size_t)SS * 32;
  float*  Ccat  = fws + o;             o += (size_t)ROWS * NCAT;       // fused qi|ki|w
  short*  BTwo  = (short*)(fws + o);   o += (size_t)1024 * KP / 2;
  short*  BTq   = (short*)(fws + o);   o += (size_t)3072 * KP / 2;
  short*  Ax    = (short*)(fws + o);                                   // aliased (ROWS*KP shorts):
  float*  attnO = fws + o;                                             //  attnO reuses Ax
  float*  Wcat  = fws + o + (size_t)ROWS * 1024;                       //  Wcat in dead tail of Ax
  /* region size */                    o += (size_t)ROWS * KP / 2;
  float*  Cbuf  = fws + o;                                             // aliased (ROWS*3072 floats):
  short*  Aattn = (short*)(fws + o);                                   //  Aattn reuses Cbuf[0..6.3M fl)
  __half* VhT   = (__half*)(fws + o + (size_t)8 * 1024 * 1024);        //  VhT at +8M fl (2.1M fl)
  u32*    msk   = (u32*)(fws + o + (size_t)10500 * 1024);              //  msk at +10.5M fl (0.26M fl)
  o += (size_t)ROWS * 3072;

  rope_tab_k<<<dim3((SS * 32 + 255) / 256), dim3(256), 0, stream>>>(ct, st);

  // packs for the two MFMA GEMMs
  pack_a_k<<<dim3(ROWS * KDIM / 4 / 256), dim3(256), 0, stream>>>(x, Ax, ROWS * KDIM / 4);
  pack_bt_k<<<dim3(3072 / 32, 32), dim3(256), 0, stream>>>(Wqkv, BTq, 3072);
  pack_bt_k<<<dim3(1024 / 32, 32), dim3(256), 0, stream>>>(Wo, BTwo, 1024);

  // qkv GEMM (split-bf16 MFMA): Cbuf[4096][3072] = x * Wqkv   (last use of Ax)
  gemm_bf16<<<dim3(3072 / 128, ROWS / 128), dim3(256), 0, stream>>>(
      Ax, BTq, Cbuf, ROWS, 3072, KP);
  qkv_post_k<<<dim3((ROWS * 384 + 255) / 256), dim3(256), 0, stream>>>(Cbuf, ct, st, Qh, Kh, Vh);
  vt_k<<<dim3(SS / 64, BB * HH), dim3(256), 0, stream>>>(Vh, VhT);

  // fused indexer projections in fp32 (bit-identical math; feeds exact top-k)
  pack_wcat_k<<<dim3((1024 * NCAT + 255) / 256), dim3(256), 0, stream>>>(Wq, Wk, Ww, Wcat);
  gemm128f<true><<<dim3(3, ROWS / 128), dim3(256), 0, stream>>>(x, Wcat, Ccat, ROWS, NCAT, 1024);

  idx_topk_k<<<dim3(SS, BB), dim3(256), 0, stream>>>(Ccat, sel);
  mask_k<<<dim3(ROWS), dim3(256), 0, stream>>>(sel, msk);
  attn_dense_k<<<dim3(1024), dim3(256), 0, stream>>>(Qh, Kh, VhT, msk, attnO);

  // out = attn @ Wo (split-bf16 MFMA)
  pack_a_k<<<dim3(ROWS * KDIM / 4 / 256), dim3(256), 0, stream>>>(attnO, Aattn, ROWS * KDIM / 4);
  gemm_bf16<<<dim3(1024 / 128, ROWS / 128), dim3(256), 0, stream>>>(
      Aattn, BTwo, out, ROWS, 1024, KP);
}

// Round 9
// 603.999 us; speedup vs baseline: 1.5739x; 1.1087x over previous
//
#include <hip/hip_runtime.h>
#include <hip/hip_fp16.h>
#include <hip/hip_bf16.h>
#include <math.h>

#define BB 2
#define SS 2048
#define HH 16
#define TOPK 512
#define ROWS (BB*SS)
#define KDIM 1024
#define KP 3072      // 3*KDIM (split-bf16 tripled K)
#define NSTR 384     // 256 qi | 64 ki | 4 w | 60 zero-pad

using bf16x8 = __attribute__((ext_vector_type(8))) short;
using f32x4  = __attribute__((ext_vector_type(4))) float;
typedef _Float16 f16x8 __attribute__((ext_vector_type(8)));
typedef unsigned int u32;

__device__ __forceinline__ void gload16(const void* g, void* l) {
  __builtin_amdgcn_global_load_lds(
      (const __attribute__((address_space(1))) u32*)g,
      (__attribute__((address_space(3))) u32*)l, 16, 0, 0);
}

__device__ __forceinline__ void split_bf16(float f, short& hi, short& lo) {
  __hip_bfloat16 h = __float2bfloat16(f);
  float fh = __bfloat162float(h);
  __hip_bfloat16 l = __float2bfloat16(f - fh);
  hi = *reinterpret_cast<short*>(&h);
  lo = *reinterpret_cast<short*>(&l);
}

__device__ __forceinline__ unsigned fkey(float f) {
  unsigned u = __float_as_uint(f);
  if ((u << 1) == 0u) u = 0u;             // canonicalize -0.0 -> +0.0
  return (u & 0x80000000u) ? ~u : (u | 0x80000000u);
}

__global__ void rope_tab_k(float* __restrict__ ct, float* __restrict__ st) {
  int idx = blockIdx.x * blockDim.x + threadIdx.x;
  if (idx >= SS * 32) return;
  int s = idx >> 5, j = idx & 31;
  float theta = 1.0f / powf(10000.0f, (float)(2 * j) / 64.0f);
  float ang = (float)s * theta;
  float sv, cv;
  sincosf(ang, &sv, &cv);
  ct[idx] = cv;
  st[idx] = sv;
}

// X[M][1024] fp32 -> A[M][3072] bf16 triplets (hi,hi,lo)
__global__ __launch_bounds__(256) void pack_a_k(
    const float* __restrict__ X, short* __restrict__ A, int total4)
{
  int idx = blockIdx.x * 256 + threadIdx.x;
  if (idx >= total4) return;
  float4 v = ((const float4*)X)[idx];
  float a4[4] = {v.x, v.y, v.z, v.w};
  short o[12];
#pragma unroll
  for (int j = 0; j < 4; ++j) {
    short hs, ls; split_bf16(a4[j], hs, ls);
    o[3*j] = hs; o[3*j+1] = hs; o[3*j+2] = ls;
  }
  short* op = A + (size_t)idx * 12;
  *(short4*)(op)     = *(short4*)&o[0];
  *(short4*)(op + 4) = *(short4*)&o[4];
  *(short4*)(op + 8) = *(short4*)&o[8];
}

// W[K=1024][Nw] fp32 -> BT rows [n][3072] bf16 triplets (hi,lo,hi)
__global__ __launch_bounds__(256) void pack_bt_k(
    const float* __restrict__ W, short* __restrict__ BT, int Nw)
{
  __shared__ float tile[32][33];
  int kb = blockIdx.y * 32, nb = blockIdx.x * 32;
  int tx = threadIdx.x & 31, ty = threadIdx.x >> 5;
  for (int yy = ty; yy < 32; yy += 8) {
    float v = 0.f;
    if (nb + tx < Nw) v = W[(size_t)(kb + yy) * Nw + nb + tx];
    tile[yy][tx] = v;
  }
  __syncthreads();
  for (int yy = ty; yy < 32; yy += 8) {
    int n = nb + yy;
    if (n >= Nw) continue;
    int k = kb + tx;
    float f = tile[tx][yy];
    short hs, ls; split_bf16(f, hs, ls);
    short* orow = BT + (size_t)n * KP + 3 * k;
    orow[0] = hs; orow[1] = ls; orow[2] = hs;
  }
}

// Wcat[k][0:256]=Wq, [256:320]=Wk, [320:324]=Ww, [324:384]=0
__global__ __launch_bounds__(256) void pack_wcat_k(
    const float* __restrict__ Wq, const float* __restrict__ Wk,
    const float* __restrict__ Ww, float* __restrict__ Wcat)
{
  int idx = blockIdx.x * 256 + threadIdx.x;
  if (idx >= 1024 * NSTR) return;
  int k = idx / NSTR, n = idx - k * NSTR;
  float v = 0.f;
  if (n < 256)      v = Wq[(size_t)k * 256 + n];
  else if (n < 320) v = Wk[(size_t)k * 64 + (n - 256)];
  else if (n < 324) v = Ww[(size_t)k * 4 + (n - 320)];
  Wcat[idx] = v;
}

// bf16 MFMA GEMM: C[M][N] = A[M][Kp]*BT[N][Kp]^T. 128x128, BK=64, 4 waves.
__global__ __launch_bounds__(256) void gemm_bf16(
    const short* __restrict__ A, const short* __restrict__ BT,
    float* __restrict__ C, int M, int N, int Kp)
{
  __shared__ short As[128 * 64];
  __shared__ short Bs[128 * 64];
  const int tid = threadIdx.x;
  const int lane = tid & 63;
  const int wv = tid >> 6;
  const int m0 = blockIdx.y * 128, n0 = blockIdx.x * 128;
  const int wr = (wv >> 1) * 64, wc = (wv & 1) * 64;
  f32x4 acc[4][4];
#pragma unroll
  for (int i = 0; i < 4; ++i)
#pragma unroll
    for (int j = 0; j < 4; ++j)
#pragma unroll
      for (int r = 0; r < 4; ++r) acc[i][j][r] = 0.0f;

  const int rsel = lane & 15;
  const int lrow = lane >> 3;          // 0..7
  const int lcol = (lane & 7) * 8;     // shorts
  for (int k0 = 0; k0 < Kp; k0 += 64) {
#pragma unroll
    for (int q = 0; q < 4; ++q) {
      int c = wv * 4 + q;              // chunk 0..15 (8 rows each)
      int row = c * 8 + lrow;
      gload16(A  + (size_t)(m0 + row) * Kp + k0 + lcol, &As[c * 512]);
      gload16(BT + (size_t)(n0 + row) * Kp + k0 + lcol, &Bs[c * 512]);
    }
    __syncthreads();
#pragma unroll
    for (int kk = 0; kk < 2; ++kk) {
      bf16x8 af[4], bfr[4];
      int kof = kk * 32 + (lane >> 4) * 8;
#pragma unroll
      for (int i = 0; i < 4; ++i) {
        af[i]  = *(const bf16x8*)&As[(wr + i * 16 + rsel) * 64 + kof];
        bfr[i] = *(const bf16x8*)&Bs[(wc + i * 16 + rsel) * 64 + kof];
      }
#pragma unroll
      for (int i = 0; i < 4; ++i)
#pragma unroll
        for (int j = 0; j < 4; ++j)
          acc[i][j] = __builtin_amdgcn_mfma_f32_16x16x32_bf16(af[i], bfr[j], acc[i][j], 0, 0, 0);
    }
    __syncthreads();
  }
  const int er = m0 + wr + (lane >> 4) * 4;
  const int ec = n0 + wc + rsel;
#pragma unroll
  for (int i = 0; i < 4; ++i)
#pragma unroll
    for (int j = 0; j < 4; ++j)
#pragma unroll
      for (int r = 0; r < 4; ++r)
        C[(size_t)(er + i * 16 + r) * N + ec + j * 16] = acc[i][j][r];
}

// fp32 indexer GEMM: C[M][384] = A[M][1024] * Wcat[1024][384].
// 32x64 tile, 128 threads, 4x4/thread, grid (6,128)=768 blocks.
// Per-output fmaf chain is k-ascending 0..1023 -> bit-identical to the
// previous 128x128 version (selection-exact).
__global__ __launch_bounds__(128) void gemm_idx_k(
    const float* __restrict__ A, const float* __restrict__ Bw, float* __restrict__ C)
{
  __shared__ float As[16][36];
  __shared__ float Bs[16][68];
  int n0 = blockIdx.x * 64, m0 = blockIdx.y * 32;
  int tid = threadIdx.x;
  int tr = tid >> 4;        // 0..7 -> rows tr*4..+3
  int tc = tid & 15;        // 0..15 -> cols tc*4..+3
  float acc[4][4];
#pragma unroll
  for (int i = 0; i < 4; ++i)
#pragma unroll
    for (int j = 0; j < 4; ++j) acc[i][j] = 0.f;

  for (int k0 = 0; k0 < 1024; k0 += 16) {
    {
      int lin = tid * 4;
      int row = lin >> 4, kk = lin & 15;
      float4 av = *(const float4*)(A + (size_t)(m0 + row) * 1024 + k0 + kk);
      As[kk + 0][row] = av.x; As[kk + 1][row] = av.y;
      As[kk + 2][row] = av.z; As[kk + 3][row] = av.w;
      int lin2 = tid * 8;
      int bk = lin2 >> 6, bc = lin2 & 63;
      const float* bp = Bw + (size_t)(k0 + bk) * NSTR + n0 + bc;
      *(float4*)&Bs[bk][bc]     = *(const float4*)(bp);
      *(float4*)&Bs[bk][bc + 4] = *(const float4*)(bp + 4);
    }
    __syncthreads();
#pragma unroll
    for (int k = 0; k < 16; ++k) {
      float a[4], b[4];
      *(float4*)&a[0] = *(const float4*)&As[k][tr * 4];
      *(float4*)&b[0] = *(const float4*)&Bs[k][tc * 4];
#pragma unroll
      for (int i = 0; i < 4; ++i)
#pragma unroll
        for (int j = 0; j < 4; ++j)
          acc[i][j] = fmaf(a[i], b[j], acc[i][j]);
    }
    __syncthreads();
  }
#pragma unroll
  for (int i = 0; i < 4; ++i)
    *(float4*)(C + (size_t)(m0 + tr * 4 + i) * NSTR + n0 + tc * 4) = *(float4*)&acc[i][0];
}

// C[M][3072] -> RoPE(q,k) + fp16 cast; Q pre-scaled by 1/8 (logit scale).
__global__ __launch_bounds__(256) void qkv_post_k(
    const float* __restrict__ C, const float* __restrict__ ct, const float* __restrict__ st,
    __half* __restrict__ Qh, __half* __restrict__ Kh, __half* __restrict__ Vh)
{
  int idx = blockIdx.x * 256 + threadIdx.x;
  if (idx >= ROWS * 384) return;
  int m = idx / 384;
  int g = idx - m * 384;
  int col0 = g * 8;
  const float* cp = C + (size_t)m * 3072 + col0;
  float4 v0 = *(const float4*)cp;
  float4 v1 = *(const float4*)(cp + 4);
  float a[8] = {v0.x, v0.y, v0.z, v0.w, v1.x, v1.y, v1.z, v1.w};
  int sec = col0 >> 10;
  int cin = col0 & 1023;
  size_t orow = (size_t)m * 1024 + cin;
  if (sec == 2) {
    __half2 hh[4];
#pragma unroll
    for (int c = 0; c < 4; ++c) hh[c] = __floats2half2_rn(a[2*c], a[2*c+1]);
    *(float4*)(Vh + orow) = *(float4*)hh;
  } else {
    int t = m & (SS - 1);
    int jb = (cin & 63) >> 1;
    float o[8];
#pragma unroll
    for (int c = 0; c < 4; ++c) {
      float cv = ct[t * 32 + jb + c], sv = st[t * 32 + jb + c];
      float x1 = a[2*c], x2 = a[2*c+1];
      o[2*c]   = x1 * cv - x2 * sv;
      o[2*c+1] = x2 * cv + x1 * sv;
    }
    if (sec == 0) {
#pragma unroll
      for (int c = 0; c < 8; ++c) o[c] *= 0.125f;   // fold 1/sqrt(64)
    }
    __half2 hh[4];
#pragma unroll
    for (int c = 0; c < 4; ++c) hh[c] = __floats2half2_rn(o[2*c], o[2*c+1]);
    __half* dst = (sec == 0) ? Qh : Kh;
    *(float4*)(dst + orow) = *(float4*)hh;
  }
}

// Vh (b,s,h*64+d) -> VhT [(b*16+h)*64+d][s]
__global__ __launch_bounds__(256) void vt_k(
    const __half* __restrict__ Vh, __half* __restrict__ VhT)
{
  int st = blockIdx.x, bh = blockIdx.y;
  int b = bh >> 4, h = bh & 15;
  int s0 = st * 64;
  __shared__ __half tile[64][65];
  int tid = threadIdx.x;
#pragma unroll
  for (int rnd = 0; rnd < 2; ++rnd) {
    int row = (tid >> 3) + rnd * 32;
    int c8 = (tid & 7) * 8;
    *(float4*)&tile[row][c8] =
        *(const float4*)(Vh + ((size_t)b * SS + s0 + row) * 1024 + h * 64 + c8);
  }
  __syncthreads();
#pragma unroll
  for (int rnd = 0; rnd < 2; ++rnd) {
    int d = (tid >> 3) + rnd * 32;
    int s8 = (tid & 7) * 8;
    __half tmp[8];
#pragma unroll
    for (int j = 0; j < 8; ++j) tmp[j] = tile[s8 + j][d];
    *(float4*)(VhT + ((size_t)bh * 64 + d) * 2048 + s0 + s8) = *(float4*)tmp;
  }
}

// sel -> per-(b,t) 2048-bit selection mask (64 u32 words)
__global__ __launch_bounds__(256) void mask_k(
    const int* __restrict__ sel, u32* __restrict__ msk)
{
  int row = blockIdx.x;            // 0..ROWS-1
  int t = row & (SS - 1);
  int tid = threadIdx.x;
  __shared__ u32 w[64];
  if (tid < 64) w[tid] = (t < TOPK) ? ((tid < 16) ? 0xFFFFFFFFu : 0u) : 0u;
  __syncthreads();
  if (t >= TOPK) {
    for (int i = tid; i < TOPK; i += 256) {
      int s = sel[(size_t)row * TOPK + i];
      atomicOr(&w[s >> 5], 1u << (s & 31));
    }
  }
  __syncthreads();
  if (tid < 64) msk[(size_t)row * 64 + tid] = w[tid];
}

// Per (b,t): indexer scores for s<=t from Ccat (stride NSTR), exact top-512.
__global__ __launch_bounds__(256) void idx_topk_k(
    const float* __restrict__ Ccat, int* __restrict__ sel)
{
  int t = blockIdx.x, b = blockIdx.y;
  int tid = threadIdx.x;
  int* srow = sel + ((size_t)b * SS + t) * TOPK;
  if (t < TOPK) {  // -1e9 ties => selection is exactly [0..511]
    for (int i = tid; i < TOPK; i += 256) srow[i] = i;
    return;
  }
  __shared__ float sc[SS];
  __shared__ unsigned hist[256];
  __shared__ unsigned hs[256];
  __shared__ unsigned s_bsel, s_above, s_cnt;

  const float4* qrow = (const float4*)(Ccat + ((size_t)b * SS + t) * NSTR);
  const float* wrow = Ccat + ((size_t)b * SS + t) * NSTR + 320;
  float w0 = wrow[0], w1 = wrow[1], w2 = wrow[2], w3 = wrow[3];

  for (int s = tid; s <= t; s += 256) {
    const float4* kp = (const float4*)(Ccat + ((size_t)b * SS + s) * NSTR + 256);
    float a0 = 0.f, a1 = 0.f, a2 = 0.f, a3 = 0.f;
#pragma unroll
    for (int d4 = 0; d4 < 16; ++d4) {
      float4 kv = kp[d4];
      float4 q0 = qrow[d4];
      float4 q1 = qrow[16 + d4];
      float4 q2 = qrow[32 + d4];
      float4 q3 = qrow[48 + d4];
      a0 += q0.x * kv.x + q0.y * kv.y + q0.z * kv.z + q0.w * kv.w;
      a1 += q1.x * kv.x + q1.y * kv.y + q1.z * kv.z + q1.w * kv.w;
      a2 += q2.x * kv.x + q2.y * kv.y + q2.z * kv.z + q2.w * kv.w;
      a3 += q3.x * kv.x + q3.y * kv.y + q3.z * kv.z + q3.w * kv.w;
    }
    float v = fmaxf(a0, 0.f) * w0 + fmaxf(a1, 0.f) * w1 +
              fmaxf(a2, 0.f) * w2 + fmaxf(a3, 0.f) * w3;
    sc[s] = v;
  }
  __syncthreads();

  unsigned krem = TOPK;
  unsigned prefix = 0;
#pragma unroll 1
  for (int p = 0; p < 4; ++p) {
    int shift = 24 - 8 * p;
    unsigned maskAbove = (p == 0) ? 0u : (0xFFFFFFFFu << (shift + 8));
    hist[tid] = 0u;
    __syncthreads();
    for (int s = tid; s <= t; s += 256) {
      unsigned key = fkey(sc[s]);
      if ((key & maskAbove) == prefix)
        atomicAdd(&hist[(key >> shift) & 255], 1u);
    }
    __syncthreads();
    hs[tid] = hist[tid];
    __syncthreads();
#pragma unroll 1
    for (int off = 1; off < 256; off <<= 1) {
      unsigned v = (tid + off < 256) ? hs[tid + off] : 0u;
      __syncthreads();
      hs[tid] += v;
      __syncthreads();
    }
    unsigned mine = hs[tid];
    unsigned nxt = (tid < 255) ? hs[tid + 1] : 0u;
    if (mine >= krem && nxt < krem) { s_bsel = (unsigned)tid; s_above = nxt; }
    __syncthreads();
    prefix |= (s_bsel << shift);
    krem -= s_above;
    __syncthreads();
  }

  unsigned Tkey = prefix;
  unsigned kfin = krem;
  if (tid == 0) s_cnt = 0u;
  __syncthreads();
  for (int s = tid; s <= t; s += 256) {
    if (fkey(sc[s]) > Tkey) {
      unsigned pp = atomicAdd(&s_cnt, 1u);
      srow[pp] = s;
    }
  }
  __syncthreads();
  unsigned cgt = s_cnt;
  if (tid < 64) {
    unsigned taken = 0;
    for (int s0 = 0; s0 <= t && taken < kfin; s0 += 64) {
      int s = s0 + tid;
      bool pred = (s <= t) && (fkey(sc[s]) == Tkey);
      unsigned long long mba = __ballot(pred);
      unsigned pre = (unsigned)__popcll(mba & ((1ull << tid) - 1ull));
      if (pred && (taken + pre) < kfin) srow[cgt + taken + pre] = s;
      taken += (unsigned)__popcll(mba);
    }
  }
}

// Dense masked flash attention, f16 MFMA. Block = (b,h, 64-query tile).
// Iterates all 2048 keys in 64-key tiles with the 512-selected mask -> exact.
__global__ __launch_bounds__(256) void attn_dense_k(
    const __half* __restrict__ Qh, const __half* __restrict__ Kh,
    const __half* __restrict__ VhT, const u32* __restrict__ msk,
    float* __restrict__ attnO)
{
  int bid = blockIdx.x;
  int xcd = bid & 7, loc = bid >> 3;
  int bh = xcd * 4 + (loc >> 5);       // 4 (b,h) pairs per XCD -> K/V L2-resident
  int qt = loc & 31;
  int b = bh >> 4, h = bh & 15;
  int t0 = qt * 64;

  const int tid = threadIdx.x;
  const int lane = tid & 63;
  const int wv = tid >> 6;
  const int l15 = lane & 15;
  const int g = lane >> 4;

  __shared__ short lds[12800];          // Ks 4096 | Vt 4096 | Ps 4*1088 | mask 256
  short* Ks = lds;                      // [64 keys][8 chunks] XOR-swizzled
  short* Vt = lds + 4096;               // [64 dims][8 chunks] XOR-swizzled
  short* Ps = lds + 8192 + wv * 1088;   // per-wave [16 queries][68]
  u32* mlds = (u32*)(lds + 12544);      // [64 queries][2 words]

  const size_t brow = (size_t)b * SS;

  // Q A-fragments (m = this wave's 16 queries), resident in regs
  f16x8 qf0, qf1;
  {
    const __half* qp = Qh + (brow + t0 + wv * 16 + l15) * 1024 + h * 64 + g * 8;
    qf0 = *(const f16x8*)(qp);
    qf1 = *(const f16x8*)(qp + 32);
  }

  f32x4 accO[4];
#pragma unroll
  for (int n2 = 0; n2 < 4; ++n2)
#pragma unroll
    for (int r = 0; r < 4; ++r) accO[n2][r] = 0.f;
  float mRun[4] = {-1e30f, -1e30f, -1e30f, -1e30f};
  float sRun[4] = {0.f, 0.f, 0.f, 0.f};

  const int srow = lane >> 3;           // staging row within 8-row group
  const int scp  = (lane & 7) ^ srow;   // pre-swizzled source chunk

#pragma unroll 1
  for (int kt = 0; kt < 32; ++kt) {
    int kt0 = kt * 64;
    // ---- stage K tile, V^T tile (DMA, linear dest + inverse-swizzled src), mask ----
#pragma unroll
    for (int q = 0; q < 2; ++q) {
      int j = wv * 2 + q;
      gload16(Kh + (brow + kt0 + j * 8 + srow) * 1024 + h * 64 + scp * 8, Ks + j * 512);
      gload16(VhT + ((size_t)(bh * 64 + j * 8 + srow)) * 2048 + kt0 + scp * 8, Vt + j * 512);
    }
    if (tid < 128)
      mlds[tid] = msk[(brow + t0 + (tid >> 1)) * 64 + kt * 2 + (tid & 1)];
    __syncthreads();

    // ---- QK^T: D[m=query][n=key] ----
    f32x4 s4[4];
#pragma unroll
    for (int ns = 0; ns < 4; ++ns) {
#pragma unroll
      for (int r = 0; r < 4; ++r) s4[ns][r] = 0.f;
      int rowk = ns * 16 + l15;
      int cp0 = g ^ (rowk & 7);
      int cp1 = (4 + g) ^ (rowk & 7);
      f16x8 kf0 = *(const f16x8*)&Ks[rowk * 64 + cp0 * 8];
      f16x8 kf1 = *(const f16x8*)&Ks[rowk * 64 + cp1 * 8];
      s4[ns] = __builtin_amdgcn_mfma_f32_16x16x32_f16(qf0, kf0, s4[ns], 0, 0, 0);
      s4[ns] = __builtin_amdgcn_mfma_f32_16x16x32_f16(qf1, kf1, s4[ns], 0, 0, 0);
    }

    // ---- masked online softmax (per query row r; keys across l15 x ns) ----
#pragma unroll
    for (int r = 0; r < 4; ++r) {
      int qb2 = (wv * 16 + g * 4 + r) * 2;
      u32 w0 = mlds[qb2];
      u32 w1 = mlds[qb2 + 1];
      float le[4];
#pragma unroll
      for (int ns = 0; ns < 4; ++ns) {
        u32 w = (ns < 2) ? w0 : w1;
        int bit = (ns & 1) * 16 + l15;
        float l = s4[ns][r];
        le[ns] = ((w >> bit) & 1u) ? l : -1e30f;
      }
      float cm = fmaxf(fmaxf(le[0], le[1]), fmaxf(le[2], le[3]));
      cm = fmaxf(cm, __shfl_xor(cm, 1));
      cm = fmaxf(cm, __shfl_xor(cm, 2));
      cm = fmaxf(cm, __shfl_xor(cm, 4));
      cm = fmaxf(cm, __shfl_xor(cm, 8));
      float mn = fmaxf(mRun[r], cm);
      float fac = __expf(mRun[r] - mn);
      mRun[r] = mn;
      float sum = 0.f;
#pragma unroll
      for (int ns = 0; ns < 4; ++ns) {
        float ee = __expf(le[ns] - mn);
        ee = (le[ns] < -1e29f) ? 0.f : ee;   // masked -> exactly 0
        sum += ee;
        Ps[(g * 4 + r) * 68 + ns * 16 + l15] =
            (short)__half_as_ushort(__float2half_rn(ee));
      }
      sum += __shfl_xor(sum, 1);
      sum += __shfl_xor(sum, 2);
      sum += __shfl_xor(sum, 4);
      sum += __shfl_xor(sum, 8);
      sRun[r] = sRun[r] * fac + sum;
#pragma unroll
      for (int n2 = 0; n2 < 4; ++n2) accO[n2][r] *= fac;
    }

    // ---- PV: D[m=query][n=dim] += P * V ----
    f16x8 pa0, pa1;
    {
      const short* pp = &Ps[l15 * 68 + g * 8];
      float2 lo0 = *(const float2*)(pp);
      float2 hi0 = *(const float2*)(pp + 4);
      float2 lo1 = *(const float2*)(pp + 32);
      float2 hi1 = *(const float2*)(pp + 36);
      float4 c0 = make_float4(lo0.x, lo0.y, hi0.x, hi0.y);
      float4 c1 = make_float4(lo1.x, lo1.y, hi1.x, hi1.y);
      pa0 = *(const f16x8*)&c0;
      pa1 = *(const f16x8*)&c1;
    }
#pragma unroll
    for (int n2 = 0; n2 < 4; ++n2) {
      int rowd = n2 * 16 + l15;
      int cp0 = g ^ (rowd & 7);
      int cp1 = (4 + g) ^ (rowd & 7);
      f16x8 vf0 = *(const f16x8*)&Vt[rowd * 64 + cp0 * 8];
      f16x8 vf1 = *(const f16x8*)&Vt[rowd * 64 + cp1 * 8];
      accO[n2] = __builtin_amdgcn_mfma_f32_16x16x32_f16(pa0, vf0, accO[n2], 0, 0, 0);
      accO[n2] = __builtin_amdgcn_mfma_f32_16x16x32_f16(pa1, vf1, accO[n2], 0, 0, 0);
    }
    __syncthreads();
  }

#pragma unroll
  for (int r = 0; r < 4; ++r) {
    float inv = 1.0f / sRun[r];
    size_t orow = (brow + t0 + wv * 16 + g * 4 + r) * (size_t)1024 + h * 64;
#pragma unroll
    for (int n2 = 0; n2 < 4; ++n2)
      attnO[orow + n2 * 16 + l15] = accO[n2][r] * inv;
  }
}

extern "C" void kernel_launch(void* const* d_in, const int* in_sizes, int n_in,
                              void* d_out, int out_size, void* d_ws, size_t ws_size,
                              hipStream_t stream) {
  const float* x    = (const float*)d_in[0];
  const float* Wqkv = (const float*)d_in[1];
  const float* Wo   = (const float*)d_in[2];
  const float* Wq   = (const float*)d_in[3];
  const float* Wk   = (const float*)d_in[4];
  const float* Ww   = (const float*)d_in[5];
  float* out = (float*)d_out;

  float* fws = (float*)d_ws;
  size_t o = 0;
  __half* Qh    = (__half*)(fws + o);  o += (size_t)ROWS * 512;
  __half* Kh    = (__half*)(fws + o);  o += (size_t)ROWS * 512;
  __half* Vh    = (__half*)(fws + o);  o += (size_t)ROWS * 512;
  int*    sel   = (int*)(fws + o);     o += (size_t)ROWS * TOPK;
  float*  ct    = fws + o;             o += (size_t)SS * 32;
  float*  st    = fws + o;             o += (size_t)SS * 32;
  float*  Ccat  = fws + o;             o += (size_t)ROWS * NSTR;       // fused qi|ki|w (padded)
  short*  BTwo  = (short*)(fws + o);   o += (size_t)1024 * KP / 2;
  short*  BTq   = (short*)(fws + o);   o += (size_t)3072 * KP / 2;
  short*  Ax    = (short*)(fws + o);                                   // aliased (ROWS*KP shorts):
  float*  attnO = fws + o;                                             //  attnO reuses Ax
  float*  Wcat  = fws + o + (size_t)ROWS * 1024;                       //  Wcat in dead tail of Ax
  /* region size */                    o += (size_t)ROWS * KP / 2;
  float*  Cbuf  = fws + o;                                             // aliased (ROWS*3072 floats):
  short*  Aattn = (short*)(fws + o);                                   //  Aattn reuses Cbuf[0..6.3M fl)
  __half* VhT   = (__half*)(fws + o + (size_t)8 * 1024 * 1024);        //  VhT at +8M fl (2.1M fl)
  u32*    msk   = (u32*)(fws + o + (size_t)10500 * 1024);              //  msk at +10.5M fl (0.26M fl)
  o += (size_t)ROWS * 3072;

  rope_tab_k<<<dim3((SS * 32 + 255) / 256), dim3(256), 0, stream>>>(ct, st);

  // packs for the two MFMA GEMMs
  pack_a_k<<<dim3(ROWS * KDIM / 4 / 256), dim3(256), 0, stream>>>(x, Ax, ROWS * KDIM / 4);
  pack_bt_k<<<dim3(3072 / 32, 32), dim3(256), 0, stream>>>(Wqkv, BTq, 3072);
  pack_bt_k<<<dim3(1024 / 32, 32), dim3(256), 0, stream>>>(Wo, BTwo, 1024);

  // qkv GEMM (split-bf16 MFMA): Cbuf[4096][3072] = x * Wqkv   (last use of Ax)
  gemm_bf16<<<dim3(3072 / 128, ROWS / 128), dim3(256), 0, stream>>>(
      Ax, BTq, Cbuf, ROWS, 3072, KP);
  qkv_post_k<<<dim3((ROWS * 384 + 255) / 256), dim3(256), 0, stream>>>(Cbuf, ct, st, Qh, Kh, Vh);
  vt_k<<<dim3(SS / 64, BB * HH), dim3(256), 0, stream>>>(Vh, VhT);

  // fused indexer projections in fp32 (bit-identical chain; feeds exact top-k)
  pack_wcat_k<<<dim3((1024 * NSTR + 255) / 256), dim3(256), 0, stream>>>(Wq, Wk, Ww, Wcat);
  gemm_idx_k<<<dim3(NSTR / 64, ROWS / 32), dim3(128), 0, stream>>>(x, Wcat, Ccat);

  idx_topk_k<<<dim3(SS, BB), dim3(256), 0, stream>>>(Ccat, sel);
  mask_k<<<dim3(ROWS), dim3(256), 0, stream>>>(sel, msk);
  attn_dense_k<<<dim3(1024), dim3(256), 0, stream>>>(Qh, Kh, VhT, msk, attnO);

  // out = attn @ Wo (split-bf16 MFMA)
  pack_a_k<<<dim3(ROWS * KDIM / 4 / 256), dim3(256), 0, stream>>>(attnO, Aattn, ROWS * KDIM / 4);
  gemm_bf16<<<dim3(1024 / 128, ROWS / 128), dim3(256), 0, stream>>>(
      Aattn, BTwo, out, ROWS, 1024, KP);
}